// Round 10
// baseline (108.320 us; speedup 1.0000x reference)
//
#include <hip/hip_runtime.h>
#include <math.h>

typedef float f4     __attribute__((ext_vector_type(4)));
typedef float f32x4  __attribute__((ext_vector_type(4)));
typedef short bf16x8 __attribute__((ext_vector_type(8)));
typedef unsigned short u16x4 __attribute__((ext_vector_type(4)));
typedef unsigned int   u32x4 __attribute__((ext_vector_type(4)));

// Problem constants: B=4096, L=5, K=32, N=16384, U=131072, V=500000, F=256, E=256
#define NROWS   16384
#define KNEI    32
#define FDIM    256
#define TWOF    512
#define EDIM    256
#define BATCH   4096
#define UROWS   131072
#define BM      32                 // fused rows per block
#define NBLK    (NROWS / BM)       // 512 blocks

static __device__ __forceinline__ unsigned short f2bf(float x) {
    union { float f; unsigned int i; } c; c.f = x;
    unsigned int u = c.i;
    u += 0x7fffu + ((u >> 16) & 1u);      // round-to-nearest-even
    return (unsigned short)(u >> 16);
}

// ===========================================================================
// FAST PATH: single megakernel, static prep partition + device-scope gate.
// ws layout: [0,16MiB)        embed4[U][32] u32  (8 biased nibbles per u32)
//            [+16MiB,+0.5MiB) scales[U] f32      (rowmax/7)
//            [+, +256KiB)     W_bf16[256][512]
//            [+, 128B)        ctrl: [0] = blocks-done counter
// Nibble packing (per u32, covering cols 8*l32 .. +7 of a row):
//   col j   (j<4) -> bits 8j..8j+3   (  w      & 0x0F0F0F0F : bytes = cols 0..3)
//   col 4+j       -> bits 8j+4..+7   ( (w>>4)  & 0x0F0F0F0F : bytes = cols 4..7)
//   stored value = clamp(rint(v*7/m),-7,7) + 8  in [1,15]
//   dequant: v = scale*(b-8);  the -8 folds into acc -= 8*sum(v).
// Residency: 512 threads, 32KB LDS, bounds(512,4) -> grid 512 = 2 blk/CU avg,
//   all blocks co-resident; gate cannot starve.
// Gate correctness on non-coherent XCD L2s: probe is an atomic RMW (executes
//   at the device coherence point, never reads a stale line); publisher uses
//   RELEASE fetch_add; readers issue an agent-scope ACQUIRE fence after the
//   gate opens, before touching embed4/scales/Wb.
// ===========================================================================
__global__ __launch_bounds__(512, 4) void mega_kernel(
    const int* __restrict__ mask_col, const float* __restrict__ mask_val,
    const int* __restrict__ unique_nodes, const int* __restrict__ nodes,
    const float* __restrict__ table, const float* __restrict__ W,
    const float* __restrict__ bias,
    unsigned int* __restrict__ embed4, float* __restrict__ scales,
    unsigned short* __restrict__ Wb, unsigned int* __restrict__ ctrl,
    float* __restrict__ out)
{
    __shared__ unsigned short As[BM * TWOF];   // 32 KB, swizzled
    char* const As_b = (char*)As;

    const int bid  = blockIdx.x;
    const int wave = threadIdx.x >> 6;
    const int lane = threadIdx.x & 63;
    const int half = lane >> 5;
    const int l32  = lane & 31;

    // ---------------- Phase A: static prep (per block: 256 embed rows,
    //                  8 cell rows, 64 Wb quads) ---------------------------
    {
        // embed: wave handles 32 rows, 2 at a time (half-wave per row)
        const int u0 = bid * 256 + wave * 32;
        #pragma unroll 2
        for (int t = 0; t < 16; ++t) {
            const int u   = u0 + t * 2 + half;
            const int row = unique_nodes[u];
            const float* rp = table + (size_t)row * FDIM + l32 * 8;
            const f4 e0 = *(const f4*)rp;
            const f4 e1 = *(const f4*)(rp + 4);
            float m = fmaxf(
                fmaxf(fmaxf(fabsf(e0[0]), fabsf(e0[1])), fmaxf(fabsf(e0[2]), fabsf(e0[3]))),
                fmaxf(fmaxf(fabsf(e1[0]), fabsf(e1[1])), fmaxf(fabsf(e1[2]), fabsf(e1[3]))));
            #pragma unroll
            for (int s = 1; s < 32; s <<= 1) m = fmaxf(m, __shfl_xor(m, s));
            m = fmaxf(m, 1e-30f);
            const float inv = 7.0f / m;
            unsigned int w = 0;
            #pragma unroll
            for (int j = 0; j < 4; ++j) {
                const int q0 = (int)fminf(fmaxf(__builtin_rintf(e0[j] * inv), -7.f), 7.f) + 8;
                const int q1 = (int)fminf(fmaxf(__builtin_rintf(e1[j] * inv), -7.f), 7.f) + 8;
                w |= (unsigned int)q0 << (8 * j);
                w |= (unsigned int)q1 << (8 * j + 4);
            }
            embed4[((size_t)u << 5) + l32] = w;
            if (l32 == 0) scales[u] = m * (1.0f / 7.0f);
        }

        // cell: wave handles one row: out[b][0][:] = table[nodes[b][0]][:]
        const int b = bid * 8 + wave;
        const int node = nodes[b * 5];
        const f4 e = *(const f4*)(table + (size_t)node * FDIM + lane * 4);
        *(f4*)(out + (size_t)b * 5 * FDIM + lane * 4) = e;

        // Wb: wave 0 converts 64 f4-quads (this block's slice)
        if (wave == 0) {
            const int idx = bid * 64 + lane;
            const f4 wv = *(const f4*)(W + (size_t)idx * 4);
            u16x4 o;
            #pragma unroll
            for (int j = 0; j < 4; ++j) o[j] = f2bf(wv[j]);
            *(u16x4*)(Wb + (size_t)idx * 4) = o;
        }
    }

    // ---------------- gate: all blocks' prep visible ------------------------
    __syncthreads();   // drains vmcnt: this block's stores are complete
    if (threadIdx.x == 0) {
        // release: publish this block's prep
        __hip_atomic_fetch_add(&ctrl[0], 1u, __ATOMIC_RELEASE,
                               __HIP_MEMORY_SCOPE_AGENT);
        // probe with an RMW: executes at the coherence point, never stale
        while (__hip_atomic_fetch_add(&ctrl[0], 0u, __ATOMIC_RELAXED,
                                      __HIP_MEMORY_SCOPE_AGENT) < (unsigned)NBLK)
            __builtin_amdgcn_s_sleep(16);
        // acquire: invalidate caches so embed4/scales/Wb reads are fresh
        __builtin_amdgcn_fence(__ATOMIC_ACQUIRE, "agent");
    }
    __syncthreads();

    // ---------------- Phase 1: gather into swizzled LDS -------------------
    const int rbase = bid * BM;

    #pragma unroll
    for (int p = 0; p < 2; ++p) {
        const int lr = wave * 4 + p * 2;       // local row (pair base)
        const int gi = rbase + lr;             // global row (pair base)

        // lanes 0..31 -> row gi's 32 entries; lanes 32..63 -> row gi+1's
        const int j   = gi * KNEI + lane;
        const int col = mask_col[j];
        const float val = mask_val[j] * scales[col];   // fold dequant scale

        // self row for this half-wave (independent: issue early)
        const int i_g = gi + half;
        const int nfr = nodes[(i_g >> 2) * 5 + 1 + (i_g & 3)];
        const float* sp = table + (size_t)nfr * FDIM + l32 * 8;
        const f4 s0 = *(const f4*)sp;
        const f4 s1 = *(const f4*)(sp + 4);

        f4 accA = (f4){0.f,0.f,0.f,0.f};   // cols 8*l32+0..3
        f4 accB = (f4){0.f,0.f,0.f,0.f};   // cols 8*l32+4..7
        float vsum = 0.0f;
        #pragma unroll 8
        for (int k = 0; k < KNEI; ++k) {
            const int   c = __shfl(col, (lane & 32) + k);
            const float v = __shfl(val, (lane & 32) + k);
            const unsigned int w  = embed4[((size_t)c << 5) + l32];  // 8 nibbles
            const unsigned int lo =  w       & 0x0F0F0F0Fu;
            const unsigned int hi = (w >> 4) & 0x0F0F0F0Fu;
            accA[0] += v * (float)( lo        & 0xFFu);   // v_cvt_f32_ubyte0
            accA[1] += v * (float)((lo >>  8) & 0xFFu);
            accA[2] += v * (float)((lo >> 16) & 0xFFu);
            accA[3] += v * (float)( lo >> 24        );
            accB[0] += v * (float)( hi        & 0xFFu);
            accB[1] += v * (float)((hi >>  8) & 0xFFu);
            accB[2] += v * (float)((hi >> 16) & 0xFFu);
            accB[3] += v * (float)( hi >> 24        );
            vsum += v;
        }
        const float c8 = 8.0f * vsum;          // bias correction
        #pragma unroll
        for (int d = 0; d < 4; ++d) { accA[d] -= c8; accB[d] -= c8; }

        const int lrow = lr + half;
        const int swz  = (lrow & 7) << 4;

        // neigh half: cols 8*l32..+8 -> bytes l32*16 (^swz)
        u32x4 on;
        on[0] = (unsigned)f2bf(accA[0]) | ((unsigned)f2bf(accA[1]) << 16);
        on[1] = (unsigned)f2bf(accA[2]) | ((unsigned)f2bf(accA[3]) << 16);
        on[2] = (unsigned)f2bf(accB[0]) | ((unsigned)f2bf(accB[1]) << 16);
        on[3] = (unsigned)f2bf(accB[2]) | ((unsigned)f2bf(accB[3]) << 16);
        *(u32x4*)(As_b + lrow * 1024 + ((l32 * 16) ^ swz)) = on;

        // self half: cols 256+8*l32 -> bytes 512+l32*16 (^swz)
        u32x4 os;
        os[0] = (unsigned)f2bf(s0[0]) | ((unsigned)f2bf(s0[1]) << 16);
        os[1] = (unsigned)f2bf(s0[2]) | ((unsigned)f2bf(s0[3]) << 16);
        os[2] = (unsigned)f2bf(s1[0]) | ((unsigned)f2bf(s1[1]) << 16);
        os[3] = (unsigned)f2bf(s1[2]) | ((unsigned)f2bf(s1[3]) << 16);
        *(u32x4*)(As_b + lrow * 1024 + ((512 + l32 * 16) ^ swz)) = os;
    }

    __syncthreads();

    // ---------------- Phase 2: MFMA (wave-tile 32 x 32) --------------------
    const int n_w    = wave * 32;
    const int lrow16 = lane & 15;
    const int koff   = (lane >> 4) * 8;
    const int aswz   = (lrow16 & 7) << 4;

    f32x4 acc[2][2] = {};
    const unsigned short* wp = Wb + (size_t)(n_w + lrow16) * TWOF + koff;

    #pragma unroll 4
    for (int kb = 0; kb < TWOF; kb += 32) {
        const int kbyte = (koff + kb) * 2;
        const bf16x8 a0 = *(const bf16x8*)(As_b + (lrow16     ) * 1024 + (kbyte ^ aswz));
        const bf16x8 a1 = *(const bf16x8*)(As_b + (lrow16 + 16) * 1024 + (kbyte ^ aswz));
        const bf16x8 b0 = *(const bf16x8*)(wp + kb);
        const bf16x8 b1 = *(const bf16x8*)(wp + 16 * TWOF + kb);
        acc[0][0] = __builtin_amdgcn_mfma_f32_16x16x32_bf16(a0, b0, acc[0][0], 0, 0, 0);
        acc[0][1] = __builtin_amdgcn_mfma_f32_16x16x32_bf16(a0, b1, acc[0][1], 0, 0, 0);
        acc[1][0] = __builtin_amdgcn_mfma_f32_16x16x32_bf16(a1, b0, acc[1][0], 0, 0, 0);
        acc[1][1] = __builtin_amdgcn_mfma_f32_16x16x32_bf16(a1, b1, acc[1][1], 0, 0, 0);
    }

    float bn[2];
    #pragma unroll
    for (int ni = 0; ni < 2; ++ni) bn[ni] = bias[n_w + ni * 16 + lrow16];

    // C/D layout: col = lane&15, row = (lane>>4)*4 + j   [verified rounds 2-7]
    #pragma unroll
    for (int mi = 0; mi < 2; ++mi) {
        #pragma unroll
        for (int ni = 0; ni < 2; ++ni) {
            const int n = n_w + ni * 16 + lrow16;
            #pragma unroll
            for (int j = 0; j < 4; ++j) {
                const int i = rbase + mi * 16 + (lane >> 4) * 4 + j;
                float h = acc[mi][ni][j] + bn[ni];
                h = h / (1.0f + __expf(-h));
                out[((size_t)(i >> 2) * 5 + 1 + (i & 3)) * FDIM + n] = h;
            }
        }
    }
}

// ===========================================================================
// FALLBACK PATH (all-f32) — used only if ws_size is too small
// ===========================================================================
__global__ __launch_bounds__(256) void neigh_f32_kernel(
    const int* __restrict__ mask_col, const float* __restrict__ mask_val,
    const int* __restrict__ unique_nodes, const float* __restrict__ table,
    float* __restrict__ neigh)
{
    const int wave = threadIdx.x >> 6;
    const int lane = threadIdx.x & 63;
    const int i = blockIdx.x * 4 + wave;
    int   row_l = 0;
    float val_l = 0.0f;
    if (lane < KNEI) {
        const int j = i * KNEI + lane;
        const int c = mask_col[j];
        val_l = mask_val[j];
        row_l = unique_nodes[c];
    }
    f4 acc = (f4){0.f, 0.f, 0.f, 0.f};
    #pragma unroll 8
    for (int k = 0; k < KNEI; ++k) {
        const int   row = __shfl(row_l, k);
        const float v   = __shfl(val_l, k);
        const f4 e = *(const f4*)(table + (size_t)row * FDIM + lane * 4);
        acc += v * e;
    }
    *(f4*)(neigh + (size_t)i * FDIM + lane * 4) = acc;
}

__global__ __launch_bounds__(256) void cell_kernel(
    const int* __restrict__ nodes, const float* __restrict__ table,
    float* __restrict__ out)
{
    const int wave = threadIdx.x >> 6;
    const int lane = threadIdx.x & 63;
    const int b = blockIdx.x * 4 + wave;
    const int node = nodes[b * 5];
    const f4 e = *(const f4*)(table + (size_t)node * FDIM + lane * 4);
    *(f4*)(out + (size_t)b * 5 * FDIM + lane * 4) = e;
}

__global__ __launch_bounds__(256) void gemm_f32_kernel(
    const float* __restrict__ neigh, const float* __restrict__ table,
    const int* __restrict__ nodes, const float* __restrict__ W,
    const float* __restrict__ bias, float* __restrict__ out)
{
    __shared__ float Asf[16][64];
    __shared__ float Wsf[16][64];
    const int t  = threadIdx.x;
    const int i0 = blockIdx.x * 64;
    const int e0 = blockIdx.y * 64;
    const int r  = t >> 2;
    const int k4 = (t & 3) << 2;
    const int irow = i0 + r;
    const int nfr = nodes[(irow >> 2) * 5 + 1 + (irow & 3)];
    const int tm = (t >> 4) << 2;
    const int tn = (t & 15) << 2;
    float acc[4][4] = {};
    for (int kb = 0; kb < TWOF; kb += 16) {
        const float* asrc = (kb < FDIM)
            ? (neigh + (size_t)irow * FDIM + kb + k4)
            : (table + (size_t)nfr  * FDIM + (kb - FDIM) + k4);
        const f4 av = *(const f4*)asrc;
        const f4 wv = *(const f4*)(W + (size_t)(e0 + r) * TWOF + kb + k4);
        __syncthreads();
        #pragma unroll
        for (int j = 0; j < 4; ++j) { Asf[k4 + j][r] = av[j]; Wsf[k4 + j][r] = wv[j]; }
        __syncthreads();
        #pragma unroll
        for (int k = 0; k < 16; ++k) {
            const f4 a = *(const f4*)&Asf[k][tm];
            const f4 w = *(const f4*)&Wsf[k][tn];
            #pragma unroll
            for (int mi = 0; mi < 4; ++mi)
                #pragma unroll
                for (int ni = 0; ni < 4; ++ni)
                    acc[mi][ni] += a[mi] * w[ni];
        }
    }
    #pragma unroll
    for (int mi = 0; mi < 4; ++mi) {
        const int i  = i0 + tm + mi;
        float* op = out + ((size_t)(i >> 2) * 5 + 1 + (i & 3)) * FDIM + e0 + tn;
        f4 hv;
        #pragma unroll
        for (int ni = 0; ni < 4; ++ni) {
            const float h = acc[mi][ni] + bias[e0 + tn + ni];
            hv[ni] = h / (1.0f + __expf(-h));
        }
        *(f4*)op = hv;
    }
}

// ===========================================================================
extern "C" void kernel_launch(void* const* d_in, const int* in_sizes, int n_in,
                              void* d_out, int out_size, void* d_ws, size_t ws_size,
                              hipStream_t stream)
{
    const int*   nodes        = (const int*)  d_in[0];
    const int*   mask_col     = (const int*)  d_in[2];
    const float* mask_val     = (const float*)d_in[3];
    const int*   unique_nodes = (const int*)  d_in[4];
    const float* table        = (const float*)d_in[5];
    const float* W            = (const float*)d_in[6];
    const float* bias         = (const float*)d_in[7];
    float*       out          = (float*)d_out;

    const size_t EMBED4_B = (size_t)UROWS * 128;              // 16 MiB int4 rows
    const size_t SC_B     = (size_t)UROWS * 4;                // 0.5 MiB scales
    const size_t W_B      = (size_t)EDIM  * TWOF * 2;         // 256 KiB
    const size_t CTRL_B   = 128;

    if (ws_size >= EMBED4_B + SC_B + W_B + CTRL_B) {
        unsigned int*   embed4 = (unsigned int*)d_ws;
        float*          scales = (float*)((char*)d_ws + EMBED4_B);
        unsigned short* Wb     = (unsigned short*)((char*)d_ws + EMBED4_B + SC_B);
        unsigned int*   ctrl   = (unsigned int*)((char*)d_ws + EMBED4_B + SC_B + W_B);

        (void)hipMemsetAsync(ctrl, 0, CTRL_B, stream);
        mega_kernel<<<NBLK, 512, 0, stream>>>(
            mask_col, mask_val, unique_nodes, nodes, table, W, bias,
            embed4, scales, Wb, ctrl, out);
    } else {
        float* neigh = (float*)d_ws;   // 16 MB
        neigh_f32_kernel<<<NROWS / 4, 256, 0, stream>>>(mask_col, mask_val,
                                                        unique_nodes, table, neigh);
        cell_kernel     <<<BATCH / 4, 256, 0, stream>>>(nodes, table, out);
        gemm_f32_kernel <<<dim3(NROWS / 64, EDIM / 64), 256, 0, stream>>>(
            neigh, table, nodes, W, bias, out);
    }
}

// Round 11
// 62.510 us; speedup vs baseline: 1.7328x; 1.7328x over previous
//
#include <hip/hip_runtime.h>
#include <math.h>

typedef float f4     __attribute__((ext_vector_type(4)));
typedef float f32x4  __attribute__((ext_vector_type(4)));
typedef short bf16x8 __attribute__((ext_vector_type(8)));
typedef unsigned short u16x4 __attribute__((ext_vector_type(4)));
typedef unsigned int   u32x4 __attribute__((ext_vector_type(4)));

// Problem constants: B=4096, L=5, K=32, N=16384, U=131072, V=500000, F=256, E=256
#define NROWS   16384
#define KNEI    32
#define FDIM    256
#define TWOF    512
#define EDIM    256
#define BATCH   4096
#define UROWS   131072
#define BM      32         // fused rows per block

static __device__ __forceinline__ unsigned short f2bf(float x) {
    union { float f; unsigned int i; } c; c.f = x;
    unsigned int u = c.i;
    u += 0x7fffu + ((u >> 16) & 1u);      // round-to-nearest-even
    return (unsigned short)(u >> 16);
}

// ===========================================================================
// FAST PATH (two kernels — single-kernel gate measured +47us, r10)
// ws layout: [0,16MiB)        embed4[U][32] u32  (8 biased nibbles per u32)
//            [+16MiB,+0.5MiB) scales[U] f32      (rowmax/7)
//            [+, +256KiB)     W_bf16[256][512]
// Nibble packing (per u32, covering cols 8*l .. +7 of a row):
//   col j   (j<4) -> bits 8j..8j+3   (  w      & 0x0F0F0F0F : bytes = cols 0..3)
//   col 4+j       -> bits 8j+4..+7   ( (w>>4)  & 0x0F0F0F0F : bytes = cols 4..7)
//   stored value = clamp(rint(v*7/m),-7,7) + 8  in [1,15]
//   dequant: v = scale*(b-8);  the -8 folds into acc -= 8*sum(v).
// ===========================================================================

#define EMBED_PB   2048                     // blocks for embed section
#define CELL_PB    64                       // blocks for cell section
#define WCONV_PB   8                        // blocks for wconv section
#define ROWS_PW    16                       // rows per wave (embed/cell)

__global__ __launch_bounds__(256) void prep_kernel(
    const int* __restrict__ unique_nodes, const float* __restrict__ table,
    const int* __restrict__ nodes, const float* __restrict__ W,
    unsigned int* __restrict__ embed4, float* __restrict__ scales,
    float* __restrict__ out, unsigned short* __restrict__ Wb)
{
    const int wave = threadIdx.x >> 6;
    const int lane = threadIdx.x & 63;
    const int half = lane >> 5;
    const int l32  = lane & 31;
    const int blk  = blockIdx.x;

    if (blk < EMBED_PB) {
        // int4 biased quantization; half-wave per row, 2 rows in flight
        const int u0 = (blk * 4 + wave) * ROWS_PW;
        #pragma unroll 2
        for (int t = 0; t < ROWS_PW / 2; ++t) {
            const int u   = u0 + t * 2 + half;
            const int row = unique_nodes[u];
            const float* rp = table + (size_t)row * FDIM + l32 * 8;
            const f4 e0 = *(const f4*)rp;
            const f4 e1 = *(const f4*)(rp + 4);
            float m = fmaxf(
                fmaxf(fmaxf(fabsf(e0[0]), fabsf(e0[1])), fmaxf(fabsf(e0[2]), fabsf(e0[3]))),
                fmaxf(fmaxf(fabsf(e1[0]), fabsf(e1[1])), fmaxf(fabsf(e1[2]), fabsf(e1[3]))));
            #pragma unroll
            for (int s = 1; s < 32; s <<= 1) m = fmaxf(m, __shfl_xor(m, s));
            m = fmaxf(m, 1e-30f);
            const float inv = 7.0f / m;
            unsigned int w = 0;
            #pragma unroll
            for (int j = 0; j < 4; ++j) {
                const int q0 = (int)fminf(fmaxf(__builtin_rintf(e0[j] * inv), -7.f), 7.f) + 8;
                const int q1 = (int)fminf(fmaxf(__builtin_rintf(e1[j] * inv), -7.f), 7.f) + 8;
                w |= (unsigned int)q0 << (8 * j);
                w |= (unsigned int)q1 << (8 * j + 4);
            }
            embed4[((size_t)u << 5) + l32] = w;
            if (l32 == 0) scales[u] = m * (1.0f / 7.0f);
        }
    } else if (blk < EMBED_PB + CELL_PB) {
        // out[b][0][:] = table[nodes[b][0]][:]  (exact f32 copy)
        const int b0 = ((blk - EMBED_PB) * 4 + wave) * ROWS_PW;
        #pragma unroll 4
        for (int t = 0; t < ROWS_PW; ++t) {
            const int b = b0 + t;
            const int node = nodes[b * 5];
            const f4 e = *(const f4*)(table + (size_t)node * FDIM + lane * 4);
            *(f4*)(out + (size_t)b * 5 * FDIM + lane * 4) = e;
        }
    } else {
        // Wb = bf16(W): 32768 f4-quads over 8 blocks x 256 threads x 16 iters
        const int base = (blk - EMBED_PB - CELL_PB) * 256 * 16 + threadIdx.x;
        #pragma unroll 4
        for (int t = 0; t < 16; ++t) {
            const int idx = base + t * 256;
            const f4 w = *(const f4*)(W + (size_t)idx * 4);
            u16x4 o;
            #pragma unroll
            for (int j = 0; j < 4; ++j) o[j] = f2bf(w[j]);
            *(u16x4*)(Wb + (size_t)idx * 4) = o;
        }
    }
}

// Fused gather + GEMM + SiLU. Block = 512 threads (8 waves), owns BM=32 rows.
// Phase 1: int4 gather into XOR-swizzled LDS A-tile (bf16, 32 KB).
//   Pair-wise: half-wave per row; per k-iter each lane loads 4 B = 8 nibbles
//   (cols 8*l32..+8) of one embed row (128 B/row visit = 1 cache line).
//   Biased decode: 2x and/shr + 8x v_cvt_f32_ubyte + 8 fma + bias fold.
// Phase 2: mfma_f32_16x16x32_bf16; A-frags ds_read_b128 from LDS (swizzled,
//   conflict-free), B-frags direct from L2-resident Wb. Wave-tile 32x32.
// Swizzle: byte(r,2k) = r*1024 + ((2k) ^ ((r&7)<<4)); all accesses 16B-aligned.
__global__ __launch_bounds__(512, 4) void fused_kernel(
    const int* __restrict__ mask_col, const float* __restrict__ mask_val,
    const unsigned int* __restrict__ embed4, const float* __restrict__ scales,
    const int* __restrict__ nodes, const float* __restrict__ table,
    const unsigned short* __restrict__ Wb, const float* __restrict__ bias,
    float* __restrict__ out)
{
    __shared__ unsigned short As[BM * TWOF];   // 32 KB, swizzled
    char* const As_b = (char*)As;

    const int wave  = threadIdx.x >> 6;
    const int lane  = threadIdx.x & 63;
    const int half  = lane >> 5;       // 0/1: which row of the pair
    const int l32   = lane & 31;
    const int rbase = blockIdx.x * BM;

    // ---------------- Phase 1: gather (2 pairs = 4 rows per wave) ----------
    #pragma unroll
    for (int p = 0; p < 2; ++p) {
        const int lr = wave * 4 + p * 2;       // local row (pair base)
        const int gi = rbase + lr;             // global row (pair base)

        // lanes 0..31 -> row gi's 32 entries; lanes 32..63 -> row gi+1's
        const int j   = gi * KNEI + lane;
        const int col = mask_col[j];
        const float val = mask_val[j] * scales[col];   // fold dequant scale

        // self row for this half-wave (independent: issue early)
        const int i_g = gi + half;
        const int nfr = nodes[(i_g >> 2) * 5 + 1 + (i_g & 3)];
        const float* sp = table + (size_t)nfr * FDIM + l32 * 8;
        const f4 s0 = *(const f4*)sp;
        const f4 s1 = *(const f4*)(sp + 4);

        f4 accA = (f4){0.f,0.f,0.f,0.f};   // cols 8*l32+0..3
        f4 accB = (f4){0.f,0.f,0.f,0.f};   // cols 8*l32+4..7
        float vsum = 0.0f;
        #pragma unroll 8
        for (int k = 0; k < KNEI; ++k) {
            const int   c = __shfl(col, (lane & 32) + k);
            const float v = __shfl(val, (lane & 32) + k);
            const unsigned int w  = embed4[((size_t)c << 5) + l32];  // 8 nibbles
            const unsigned int lo =  w       & 0x0F0F0F0Fu;
            const unsigned int hi = (w >> 4) & 0x0F0F0F0Fu;
            accA[0] += v * (float)( lo        & 0xFFu);   // v_cvt_f32_ubyte0
            accA[1] += v * (float)((lo >>  8) & 0xFFu);
            accA[2] += v * (float)((lo >> 16) & 0xFFu);
            accA[3] += v * (float)( lo >> 24        );
            accB[0] += v * (float)( hi        & 0xFFu);
            accB[1] += v * (float)((hi >>  8) & 0xFFu);
            accB[2] += v * (float)((hi >> 16) & 0xFFu);
            accB[3] += v * (float)( hi >> 24        );
            vsum += v;
        }
        const float c8 = 8.0f * vsum;          // bias correction
        #pragma unroll
        for (int d = 0; d < 4; ++d) { accA[d] -= c8; accB[d] -= c8; }

        const int lrow = lr + half;
        const int swz  = (lrow & 7) << 4;

        // neigh half: cols 8*l32..+8 -> bytes l32*16 (^swz)
        u32x4 on;
        on[0] = (unsigned)f2bf(accA[0]) | ((unsigned)f2bf(accA[1]) << 16);
        on[1] = (unsigned)f2bf(accA[2]) | ((unsigned)f2bf(accA[3]) << 16);
        on[2] = (unsigned)f2bf(accB[0]) | ((unsigned)f2bf(accB[1]) << 16);
        on[3] = (unsigned)f2bf(accB[2]) | ((unsigned)f2bf(accB[3]) << 16);
        *(u32x4*)(As_b + lrow * 1024 + ((l32 * 16) ^ swz)) = on;

        // self half: cols 256+8*l32 -> bytes 512+l32*16 (^swz)
        u32x4 os;
        os[0] = (unsigned)f2bf(s0[0]) | ((unsigned)f2bf(s0[1]) << 16);
        os[1] = (unsigned)f2bf(s0[2]) | ((unsigned)f2bf(s0[3]) << 16);
        os[2] = (unsigned)f2bf(s1[0]) | ((unsigned)f2bf(s1[1]) << 16);
        os[3] = (unsigned)f2bf(s1[2]) | ((unsigned)f2bf(s1[3]) << 16);
        *(u32x4*)(As_b + lrow * 1024 + ((512 + l32 * 16) ^ swz)) = os;
    }

    __syncthreads();

    // ---------------- Phase 2: MFMA (wave-tile 32 x 32) --------------------
    const int n_w    = wave * 32;
    const int lrow16 = lane & 15;
    const int koff   = (lane >> 4) * 8;
    const int aswz   = (lrow16 & 7) << 4;

    f32x4 acc[2][2] = {};
    const unsigned short* wp = Wb + (size_t)(n_w + lrow16) * TWOF + koff;

    #pragma unroll 4
    for (int kb = 0; kb < TWOF; kb += 32) {
        const int kbyte = (koff + kb) * 2;
        const bf16x8 a0 = *(const bf16x8*)(As_b + (lrow16     ) * 1024 + (kbyte ^ aswz));
        const bf16x8 a1 = *(const bf16x8*)(As_b + (lrow16 + 16) * 1024 + (kbyte ^ aswz));
        const bf16x8 b0 = *(const bf16x8*)(wp + kb);
        const bf16x8 b1 = *(const bf16x8*)(wp + 16 * TWOF + kb);
        acc[0][0] = __builtin_amdgcn_mfma_f32_16x16x32_bf16(a0, b0, acc[0][0], 0, 0, 0);
        acc[0][1] = __builtin_amdgcn_mfma_f32_16x16x32_bf16(a0, b1, acc[0][1], 0, 0, 0);
        acc[1][0] = __builtin_amdgcn_mfma_f32_16x16x32_bf16(a1, b0, acc[1][0], 0, 0, 0);
        acc[1][1] = __builtin_amdgcn_mfma_f32_16x16x32_bf16(a1, b1, acc[1][1], 0, 0, 0);
    }

    float bn[2];
    #pragma unroll
    for (int ni = 0; ni < 2; ++ni) bn[ni] = bias[n_w + ni * 16 + lrow16];

    // C/D layout: col = lane&15, row = (lane>>4)*4 + j   [verified rounds 2-7]
    #pragma unroll
    for (int mi = 0; mi < 2; ++mi) {
        #pragma unroll
        for (int ni = 0; ni < 2; ++ni) {
            const int n = n_w + ni * 16 + lrow16;
            #pragma unroll
            for (int j = 0; j < 4; ++j) {
                const int i = rbase + mi * 16 + (lane >> 4) * 4 + j;
                float h = acc[mi][ni][j] + bn[ni];
                h = h / (1.0f + __expf(-h));
                out[((size_t)(i >> 2) * 5 + 1 + (i & 3)) * FDIM + n] = h;
            }
        }
    }
}

// ===========================================================================
// FALLBACK PATH (all-f32) — used only if ws_size is too small
// ===========================================================================
__global__ __launch_bounds__(256) void neigh_f32_kernel(
    const int* __restrict__ mask_col, const float* __restrict__ mask_val,
    const int* __restrict__ unique_nodes, const float* __restrict__ table,
    float* __restrict__ neigh)
{
    const int wave = threadIdx.x >> 6;
    const int lane = threadIdx.x & 63;
    const int i = blockIdx.x * 4 + wave;
    int   row_l = 0;
    float val_l = 0.0f;
    if (lane < KNEI) {
        const int j = i * KNEI + lane;
        const int c = mask_col[j];
        val_l = mask_val[j];
        row_l = unique_nodes[c];
    }
    f4 acc = (f4){0.f, 0.f, 0.f, 0.f};
    #pragma unroll 8
    for (int k = 0; k < KNEI; ++k) {
        const int   row = __shfl(row_l, k);
        const float v   = __shfl(val_l, k);
        const f4 e = *(const f4*)(table + (size_t)row * FDIM + lane * 4);
        acc += v * e;
    }
    *(f4*)(neigh + (size_t)i * FDIM + lane * 4) = acc;
}

__global__ __launch_bounds__(256) void cell_kernel(
    const int* __restrict__ nodes, const float* __restrict__ table,
    float* __restrict__ out)
{
    const int wave = threadIdx.x >> 6;
    const int lane = threadIdx.x & 63;
    const int b = blockIdx.x * 4 + wave;
    const int node = nodes[b * 5];
    const f4 e = *(const f4*)(table + (size_t)node * FDIM + lane * 4);
    *(f4*)(out + (size_t)b * 5 * FDIM + lane * 4) = e;
}

__global__ __launch_bounds__(256) void gemm_f32_kernel(
    const float* __restrict__ neigh, const float* __restrict__ table,
    const int* __restrict__ nodes, const float* __restrict__ W,
    const float* __restrict__ bias, float* __restrict__ out)
{
    __shared__ float Asf[16][64];
    __shared__ float Wsf[16][64];
    const int t  = threadIdx.x;
    const int i0 = blockIdx.x * 64;
    const int e0 = blockIdx.y * 64;
    const int r  = t >> 2;
    const int k4 = (t & 3) << 2;
    const int irow = i0 + r;
    const int nfr = nodes[(irow >> 2) * 5 + 1 + (irow & 3)];
    const int tm = (t >> 4) << 2;
    const int tn = (t & 15) << 2;
    float acc[4][4] = {};
    for (int kb = 0; kb < TWOF; kb += 16) {
        const float* asrc = (kb < FDIM)
            ? (neigh + (size_t)irow * FDIM + kb + k4)
            : (table + (size_t)nfr  * FDIM + (kb - FDIM) + k4);
        const f4 av = *(const f4*)asrc;
        const f4 wv = *(const f4*)(W + (size_t)(e0 + r) * TWOF + kb + k4);
        __syncthreads();
        #pragma unroll
        for (int j = 0; j < 4; ++j) { Asf[k4 + j][r] = av[j]; Wsf[k4 + j][r] = wv[j]; }
        __syncthreads();
        #pragma unroll
        for (int k = 0; k < 16; ++k) {
            const f4 a = *(const f4*)&Asf[k][tm];
            const f4 w = *(const f4*)&Wsf[k][tn];
            #pragma unroll
            for (int mi = 0; mi < 4; ++mi)
                #pragma unroll
                for (int ni = 0; ni < 4; ++ni)
                    acc[mi][ni] += a[mi] * w[ni];
        }
    }
    #pragma unroll
    for (int mi = 0; mi < 4; ++mi) {
        const int i  = i0 + tm + mi;
        float* op = out + ((size_t)(i >> 2) * 5 + 1 + (i & 3)) * FDIM + e0 + tn;
        f4 hv;
        #pragma unroll
        for (int ni = 0; ni < 4; ++ni) {
            const float h = acc[mi][ni] + bias[e0 + tn + ni];
            hv[ni] = h / (1.0f + __expf(-h));
        }
        *(f4*)op = hv;
    }
}

// ===========================================================================
extern "C" void kernel_launch(void* const* d_in, const int* in_sizes, int n_in,
                              void* d_out, int out_size, void* d_ws, size_t ws_size,
                              hipStream_t stream)
{
    const int*   nodes        = (const int*)  d_in[0];
    const int*   mask_col     = (const int*)  d_in[2];
    const float* mask_val     = (const float*)d_in[3];
    const int*   unique_nodes = (const int*)  d_in[4];
    const float* table        = (const float*)d_in[5];
    const float* W            = (const float*)d_in[6];
    const float* bias         = (const float*)d_in[7];
    float*       out          = (float*)d_out;

    const size_t EMBED4_B = (size_t)UROWS * 128;              // 16 MiB int4 rows
    const size_t SC_B     = (size_t)UROWS * 4;                // 0.5 MiB scales
    const size_t W_B      = (size_t)EDIM  * TWOF * 2;         // 256 KiB

    if (ws_size >= EMBED4_B + SC_B + W_B) {
        unsigned int*   embed4 = (unsigned int*)d_ws;
        float*          scales = (float*)((char*)d_ws + EMBED4_B);
        unsigned short* Wb     = (unsigned short*)((char*)d_ws + EMBED4_B + SC_B);

        prep_kernel<<<EMBED_PB + CELL_PB + WCONV_PB, 256, 0, stream>>>(
            unique_nodes, table, nodes, W, embed4, scales, out, Wb);
        fused_kernel<<<NROWS / BM, 512, 0, stream>>>(
            mask_col, mask_val, embed4, scales, nodes, table, Wb, bias, out);
    } else {
        float* neigh = (float*)d_ws;   // 16 MB
        neigh_f32_kernel<<<NROWS / 4, 256, 0, stream>>>(mask_col, mask_val,
                                                        unique_nodes, table, neigh);
        cell_kernel     <<<BATCH / 4, 256, 0, stream>>>(nodes, table, out);
        gemm_f32_kernel <<<dim3(NROWS / 64, EDIM / 64), 256, 0, stream>>>(
            neigh, table, nodes, W, bias, out);
    }
}

// Round 12
// 60.385 us; speedup vs baseline: 1.7938x; 1.0352x over previous
//
#include <hip/hip_runtime.h>
#include <math.h>

typedef float f4     __attribute__((ext_vector_type(4)));
typedef float f32x4  __attribute__((ext_vector_type(4)));
typedef short bf16x8 __attribute__((ext_vector_type(8)));
typedef unsigned short u16x4 __attribute__((ext_vector_type(4)));
typedef unsigned int   u32x4 __attribute__((ext_vector_type(4)));

// Problem constants: B=4096, L=5, K=32, N=16384, U=131072, V=500000, F=256, E=256
#define NROWS   16384
#define KNEI    32
#define FDIM    256
#define TWOF    512
#define EDIM    256
#define BATCH   4096
#define UROWS   131072
#define BM      32         // fused-kernel rows per block

static __device__ __forceinline__ unsigned short f2bf(float x) {
    union { float f; unsigned int i; } c; c.f = x;
    unsigned int u = c.i;
    u += 0x7fffu + ((u >> 16) & 1u);      // round-to-nearest-even
    return (unsigned short)(u >> 16);
}

// ===========================================================================
// FAST PATH (best measured configuration, r7: 60.65 us)
// ws layout: [0,16MiB)        embed4[U][64] u16  (int4x4 per u16; row = 128 B)
//            [+16MiB,+0.5MiB) scales[U] f32      (rowmax/7; L2-resident)
//            [+, +256KiB)     W_bf16[256][512]
// embed4 row r, u16 index l (0..63) packs cols 4l..4l+3 as signed nibbles.
// Dequant: v = scale[r] * q;  q in [-7,7].
//
// Negative results (measured):
//   r5  quarter-wave 16B gather     : null  (fused is latency-bound, not issue)
//   r6  persistent-grid prep        : null  (prep at random-HBM floor)
//   r10 single-kernel device gate   : +47us (global sync >> launch gap)
//   r11 biased-nibble ubyte decode  : +1.9us (gather not VALU-bound)
// ===========================================================================

#define EMBED_PB   2048                     // blocks for embed section
#define CELL_PB    64                       // blocks for cell section
#define WCONV_PB   8                        // blocks for wconv section
#define ROWS_PW    16                       // rows per wave (embed/cell)

__global__ __launch_bounds__(256) void prep_kernel(
    const int* __restrict__ unique_nodes, const float* __restrict__ table,
    const int* __restrict__ nodes, const float* __restrict__ W,
    unsigned short* __restrict__ embed4, float* __restrict__ scales,
    float* __restrict__ out, unsigned short* __restrict__ Wb)
{
    const int wave = threadIdx.x >> 6;
    const int lane = threadIdx.x & 63;
    const int blk  = blockIdx.x;

    if (blk < EMBED_PB) {
        // int4 per-row symmetric quantization of table[unique_nodes[u]]
        const int u0 = (blk * 4 + wave) * ROWS_PW;
        #pragma unroll 2
        for (int t = 0; t < ROWS_PW; ++t) {
            const int u   = u0 + t;
            const int row = unique_nodes[u];
            const f4 e = *(const f4*)(table + (size_t)row * FDIM + lane * 4);
            // row max |.| over 256 values (64 lanes x 4)
            float m = fmaxf(fmaxf(fabsf(e[0]), fabsf(e[1])),
                            fmaxf(fabsf(e[2]), fabsf(e[3])));
            #pragma unroll
            for (int s = 1; s < 64; s <<= 1)
                m = fmaxf(m, __shfl_xor(m, s));
            m = fmaxf(m, 1e-30f);
            const float inv = 7.0f / m;
            unsigned short pk = 0;
            #pragma unroll
            for (int j = 0; j < 4; ++j) {
                float qf = __builtin_rintf(e[j] * inv);
                qf = fminf(fmaxf(qf, -7.0f), 7.0f);
                const int q = (int)qf;
                pk |= (unsigned short)((q & 0xF) << (4 * j));
            }
            embed4[((size_t)u << 6) + lane] = pk;
            if (lane == 0) scales[u] = m * (1.0f / 7.0f);
        }
    } else if (blk < EMBED_PB + CELL_PB) {
        // out[b][0][:] = table[nodes[b][0]][:]  (exact f32 copy)
        const int b0 = ((blk - EMBED_PB) * 4 + wave) * ROWS_PW;
        #pragma unroll 4
        for (int t = 0; t < ROWS_PW; ++t) {
            const int b = b0 + t;
            const int node = nodes[b * 5];
            const f4 e = *(const f4*)(table + (size_t)node * FDIM + lane * 4);
            *(f4*)(out + (size_t)b * 5 * FDIM + lane * 4) = e;
        }
    } else {
        // Wb = bf16(W): 32768 f4-quads over 8 blocks x 256 threads x 16 iters
        const int base = (blk - EMBED_PB - CELL_PB) * 256 * 16 + threadIdx.x;
        #pragma unroll 4
        for (int t = 0; t < 16; ++t) {
            const int idx = base + t * 256;
            const f4 w = *(const f4*)(W + (size_t)idx * 4);
            u16x4 o;
            #pragma unroll
            for (int j = 0; j < 4; ++j) o[j] = f2bf(w[j]);
            *(u16x4*)(Wb + (size_t)idx * 4) = o;
        }
    }
}

// Fused gather + GEMM + SiLU. Block = 512 threads (8 waves), owns BM=32 rows.
// Phase 1: int4 gather into XOR-swizzled LDS A-tile (bf16, 32 KB).
//   Pair-wise: half-wave per row; per k-iter each lane loads 4 B = 8 int4
//   cols (8*l32..+8) of one embed row (128 B/visit = 1 cache line).
//   Scale is folded into val in the prologue: val_eff = mask_val*scale[col].
// Phase 2: mfma_f32_16x16x32_bf16; A-frags ds_read_b128 from LDS (swizzled,
//   conflict-free), B-frags direct from L2-resident Wb. Wave-tile 32x32.
// Swizzle: byte(r,2k) = r*1024 + ((2k) ^ ((r&7)<<4)); all accesses 16B-aligned.
__global__ __launch_bounds__(512, 4) void fused_kernel(
    const int* __restrict__ mask_col, const float* __restrict__ mask_val,
    const unsigned int* __restrict__ embed4, const float* __restrict__ scales,
    const int* __restrict__ nodes, const float* __restrict__ table,
    const unsigned short* __restrict__ Wb, const float* __restrict__ bias,
    float* __restrict__ out)
{
    __shared__ unsigned short As[BM * TWOF];   // 32 KB, swizzled
    char* const As_b = (char*)As;

    const int wave  = threadIdx.x >> 6;
    const int lane  = threadIdx.x & 63;
    const int half  = lane >> 5;       // 0/1: which row of the pair
    const int l32   = lane & 31;
    const int rbase = blockIdx.x * BM;

    // ---------------- Phase 1: gather (2 pairs = 4 rows per wave) ----------
    #pragma unroll
    for (int p = 0; p < 2; ++p) {
        const int lr = wave * 4 + p * 2;       // local row (pair base)
        const int gi = rbase + lr;             // global row (pair base)

        // lanes 0..31 -> row gi's 32 entries; lanes 32..63 -> row gi+1's
        const int j   = gi * KNEI + lane;
        const int col = mask_col[j];
        const float val = mask_val[j] * scales[col];   // fold dequant scale

        // self row for this half-wave (independent: issue early)
        const int i_g = gi + half;
        const int nfr = nodes[(i_g >> 2) * 5 + 1 + (i_g & 3)];
        const float* sp = table + (size_t)nfr * FDIM + l32 * 8;
        const f4 s0 = *(const f4*)sp;
        const f4 s1 = *(const f4*)(sp + 4);

        f4 accA = (f4){0.f,0.f,0.f,0.f};   // cols 8*l32+0..3
        f4 accB = (f4){0.f,0.f,0.f,0.f};   // cols 8*l32+4..7
        #pragma unroll 8
        for (int k = 0; k < KNEI; ++k) {
            const int   c = __shfl(col, (lane & 32) + k);
            const float v = __shfl(val, (lane & 32) + k);
            const unsigned int w = embed4[((size_t)c << 5) + l32];  // 8 int4
            #pragma unroll
            for (int d = 0; d < 4; ++d) {
                const int qa = ((int)(w << (28 - 4 * d))) >> 28;
                const int qb = ((int)(w << (12 - 4 * d))) >> 28;
                accA[d] += v * (float)qa;
                accB[d] += v * (float)qb;
            }
        }

        const int lrow = lr + half;
        const int swz  = (lrow & 7) << 4;

        // neigh half: cols 8*l32..+8 -> bytes l32*16 (^swz)
        u32x4 on;
        on[0] = (unsigned)f2bf(accA[0]) | ((unsigned)f2bf(accA[1]) << 16);
        on[1] = (unsigned)f2bf(accA[2]) | ((unsigned)f2bf(accA[3]) << 16);
        on[2] = (unsigned)f2bf(accB[0]) | ((unsigned)f2bf(accB[1]) << 16);
        on[3] = (unsigned)f2bf(accB[2]) | ((unsigned)f2bf(accB[3]) << 16);
        *(u32x4*)(As_b + lrow * 1024 + ((l32 * 16) ^ swz)) = on;

        // self half: cols 256+8*l32 -> bytes 512+l32*16 (^swz)
        u32x4 os;
        os[0] = (unsigned)f2bf(s0[0]) | ((unsigned)f2bf(s0[1]) << 16);
        os[1] = (unsigned)f2bf(s0[2]) | ((unsigned)f2bf(s0[3]) << 16);
        os[2] = (unsigned)f2bf(s1[0]) | ((unsigned)f2bf(s1[1]) << 16);
        os[3] = (unsigned)f2bf(s1[2]) | ((unsigned)f2bf(s1[3]) << 16);
        *(u32x4*)(As_b + lrow * 1024 + ((512 + l32 * 16) ^ swz)) = os;
    }

    __syncthreads();

    // ---------------- Phase 2: MFMA (wave-tile 32 x 32) --------------------
    const int n_w    = wave * 32;
    const int lrow16 = lane & 15;
    const int koff   = (lane >> 4) * 8;
    const int aswz   = (lrow16 & 7) << 4;

    f32x4 acc[2][2] = {};
    const unsigned short* wp = Wb + (size_t)(n_w + lrow16) * TWOF + koff;

    #pragma unroll 4
    for (int kb = 0; kb < TWOF; kb += 32) {
        const int kbyte = (koff + kb) * 2;
        const bf16x8 a0 = *(const bf16x8*)(As_b + (lrow16     ) * 1024 + (kbyte ^ aswz));
        const bf16x8 a1 = *(const bf16x8*)(As_b + (lrow16 + 16) * 1024 + (kbyte ^ aswz));
        const bf16x8 b0 = *(const bf16x8*)(wp + kb);
        const bf16x8 b1 = *(const bf16x8*)(wp + 16 * TWOF + kb);
        acc[0][0] = __builtin_amdgcn_mfma_f32_16x16x32_bf16(a0, b0, acc[0][0], 0, 0, 0);
        acc[0][1] = __builtin_amdgcn_mfma_f32_16x16x32_bf16(a0, b1, acc[0][1], 0, 0, 0);
        acc[1][0] = __builtin_amdgcn_mfma_f32_16x16x32_bf16(a1, b0, acc[1][0], 0, 0, 0);
        acc[1][1] = __builtin_amdgcn_mfma_f32_16x16x32_bf16(a1, b1, acc[1][1], 0, 0, 0);
    }

    float bn[2];
    #pragma unroll
    for (int ni = 0; ni < 2; ++ni) bn[ni] = bias[n_w + ni * 16 + lrow16];

    // C/D layout: col = lane&15, row = (lane>>4)*4 + j   [verified rounds 2-11]
    #pragma unroll
    for (int mi = 0; mi < 2; ++mi) {
        #pragma unroll
        for (int ni = 0; ni < 2; ++ni) {
            const int n = n_w + ni * 16 + lrow16;
            #pragma unroll
            for (int j = 0; j < 4; ++j) {
                const int i = rbase + mi * 16 + (lane >> 4) * 4 + j;
                float h = acc[mi][ni][j] + bn[ni];
                h = h / (1.0f + __expf(-h));
                out[((size_t)(i >> 2) * 5 + 1 + (i & 3)) * FDIM + n] = h;
            }
        }
    }
}

// ===========================================================================
// FALLBACK PATH (all-f32) — used only if ws_size is too small
// ===========================================================================
__global__ __launch_bounds__(256) void neigh_f32_kernel(
    const int* __restrict__ mask_col, const float* __restrict__ mask_val,
    const int* __restrict__ unique_nodes, const float* __restrict__ table,
    float* __restrict__ neigh)
{
    const int wave = threadIdx.x >> 6;
    const int lane = threadIdx.x & 63;
    const int i = blockIdx.x * 4 + wave;
    int   row_l = 0;
    float val_l = 0.0f;
    if (lane < KNEI) {
        const int j = i * KNEI + lane;
        const int c = mask_col[j];
        val_l = mask_val[j];
        row_l = unique_nodes[c];
    }
    f4 acc = (f4){0.f, 0.f, 0.f, 0.f};
    #pragma unroll 8
    for (int k = 0; k < KNEI; ++k) {
        const int   row = __shfl(row_l, k);
        const float v   = __shfl(val_l, k);
        const f4 e = *(const f4*)(table + (size_t)row * FDIM + lane * 4);
        acc += v * e;
    }
    *(f4*)(neigh + (size_t)i * FDIM + lane * 4) = acc;
}

__global__ __launch_bounds__(256) void cell_kernel(
    const int* __restrict__ nodes, const float* __restrict__ table,
    float* __restrict__ out)
{
    const int wave = threadIdx.x >> 6;
    const int lane = threadIdx.x & 63;
    const int b = blockIdx.x * 4 + wave;
    const int node = nodes[b * 5];
    const f4 e = *(const f4*)(table + (size_t)node * FDIM + lane * 4);
    *(f4*)(out + (size_t)b * 5 * FDIM + lane * 4) = e;
}

__global__ __launch_bounds__(256) void gemm_f32_kernel(
    const float* __restrict__ neigh, const float* __restrict__ table,
    const int* __restrict__ nodes, const float* __restrict__ W,
    const float* __restrict__ bias, float* __restrict__ out)
{
    __shared__ float Asf[16][64];
    __shared__ float Wsf[16][64];
    const int t  = threadIdx.x;
    const int i0 = blockIdx.x * 64;
    const int e0 = blockIdx.y * 64;
    const int r  = t >> 2;
    const int k4 = (t & 3) << 2;
    const int irow = i0 + r;
    const int nfr = nodes[(irow >> 2) * 5 + 1 + (irow & 3)];
    const int tm = (t >> 4) << 2;
    const int tn = (t & 15) << 2;
    float acc[4][4] = {};
    for (int kb = 0; kb < TWOF; kb += 16) {
        const float* asrc = (kb < FDIM)
            ? (neigh + (size_t)irow * FDIM + kb + k4)
            : (table + (size_t)nfr  * FDIM + (kb - FDIM) + k4);
        const f4 av = *(const f4*)asrc;
        const f4 wv = *(const f4*)(W + (size_t)(e0 + r) * TWOF + kb + k4);
        __syncthreads();
        #pragma unroll
        for (int j = 0; j < 4; ++j) { Asf[k4 + j][r] = av[j]; Wsf[k4 + j][r] = wv[j]; }
        __syncthreads();
        #pragma unroll
        for (int k = 0; k < 16; ++k) {
            const f4 a = *(const f4*)&Asf[k][tm];
            const f4 w = *(const f4*)&Wsf[k][tn];
            #pragma unroll
            for (int mi = 0; mi < 4; ++mi)
                #pragma unroll
                for (int ni = 0; ni < 4; ++ni)
                    acc[mi][ni] += a[mi] * w[ni];
        }
    }
    #pragma unroll
    for (int mi = 0; mi < 4; ++mi) {
        const int i  = i0 + tm + mi;
        float* op = out + ((size_t)(i >> 2) * 5 + 1 + (i & 3)) * FDIM + e0 + tn;
        f4 hv;
        #pragma unroll
        for (int ni = 0; ni < 4; ++ni) {
            const float h = acc[mi][ni] + bias[e0 + tn + ni];
            hv[ni] = h / (1.0f + __expf(-h));
        }
        *(f4*)op = hv;
    }
}

// ===========================================================================
extern "C" void kernel_launch(void* const* d_in, const int* in_sizes, int n_in,
                              void* d_out, int out_size, void* d_ws, size_t ws_size,
                              hipStream_t stream)
{
    const int*   nodes        = (const int*)  d_in[0];
    const int*   mask_col     = (const int*)  d_in[2];
    const float* mask_val     = (const float*)d_in[3];
    const int*   unique_nodes = (const int*)  d_in[4];
    const float* table        = (const float*)d_in[5];
    const float* W            = (const float*)d_in[6];
    const float* bias         = (const float*)d_in[7];
    float*       out          = (float*)d_out;

    const size_t EMBED4_B = (size_t)UROWS * 128;              // 16 MiB int4 rows
    const size_t SC_B     = (size_t)UROWS * 4;                // 0.5 MiB scales
    const size_t W_B      = (size_t)EDIM  * TWOF * 2;         // 256 KiB

    if (ws_size >= EMBED4_B + SC_B + W_B) {
        unsigned short* embed4 = (unsigned short*)d_ws;
        float*          scales = (float*)((char*)d_ws + EMBED4_B);
        unsigned short* Wb     = (unsigned short*)((char*)d_ws + EMBED4_B + SC_B);

        prep_kernel<<<EMBED_PB + CELL_PB + WCONV_PB, 256, 0, stream>>>(
            unique_nodes, table, nodes, W, embed4, scales, out, Wb);
        fused_kernel<<<NROWS / BM, 512, 0, stream>>>(
            mask_col, mask_val, (const unsigned int*)embed4, scales,
            nodes, table, Wb, bias, out);
    } else {
        float* neigh = (float*)d_ws;   // 16 MB
        neigh_f32_kernel<<<NROWS / 4, 256, 0, stream>>>(mask_col, mask_val,
                                                        unique_nodes, table, neigh);
        cell_kernel     <<<BATCH / 4, 256, 0, stream>>>(nodes, table, out);
        gemm_f32_kernel <<<dim3(NROWS / 64, EDIM / 64), 256, 0, stream>>>(
            neigh, table, nodes, W, bias, out);
    }
}